// Round 6
// baseline (92.060 us; speedup 1.0000x reference)
//
#include <hip/hip_runtime.h>

// SimpleGNN: B=4, N=512, D=128, L=2
// msg[b,i,:] = (sum_j adj[b,i,j]*relu(ai'[b,i,:]+aj[b,j,:])) @ w2^T
//            + (sum_j adj[b,i,j]) * b2 ;  ai' = h@wi^T + b1, aj = h@wj^T
// msgfull: JS=1 — one block computes the COMPLETE j-sum for 8 rows, then
// applies w2 + bias + residual in-kernel (lin2 fused). Thread = (d-quad,
// j-group): one per-lane ds_read_b128 of aj feeds 96 VALU ops; adj costs
// 2 broadcast b128 per jj for the whole 8-row tile. 5 dispatches total.

constexpr int Bc = 4, Nc = 512, Dc = 128, Lc = 2;
constexpr int BN = Bc * Nc;   // 2048
constexpr int TI = 8;         // rows per msg block
constexpr int CH = 64;        // j's per staged chunk
constexpr int NCH = Nc / CH;  // 8
constexpr int TN = 4;         // rows per lin block

__global__ void transpose_w_kernel(const float* __restrict__ w1,
                                   const float* __restrict__ w2,
                                   float* __restrict__ wiT,
                                   float* __restrict__ wjT,
                                   float* __restrict__ w2T) {
    int idx = blockIdx.x * blockDim.x + threadIdx.x;
    if (idx >= Lc * Dc * Dc) return;
    int l = idx / (Dc * Dc);
    int rem = idx - l * Dc * Dc;
    int d = rem / Dc;
    int o = rem - d * Dc;
    wiT[idx] = w1[(l * Dc + o) * (2 * Dc) + d];
    wjT[idx] = w1[(l * Dc + o) * (2 * Dc) + Dc + d];
    w2T[idx] = w2[(l * Dc + o) * Dc + d];
}

// --- first linear (round-3 winner, verbatim)
__global__ __launch_bounds__(128) void gnn_lin1(const float* __restrict__ h,
                                                const float* __restrict__ wiT,
                                                const float* __restrict__ wjT,
                                                const float* __restrict__ b1,
                                                float* __restrict__ ai,
                                                float* __restrict__ aj) {
    __shared__ float hs[TN][Dc];
    const int o = threadIdx.x;
    const int r0 = blockIdx.x * TN;
#pragma unroll
    for (int t = 0; t < TN; ++t) hs[t][o] = h[(r0 + t) * Dc + o];
    __syncthreads();
    float acci[TN], accj[TN];
    const float bo = b1[o];
#pragma unroll
    for (int t = 0; t < TN; ++t) { acci[t] = bo; accj[t] = 0.f; }
    for (int d = 0; d < Dc; d += 4) {
        float wi[4], wj[4];
#pragma unroll
        for (int k = 0; k < 4; ++k) {
            wi[k] = wiT[(d + k) * Dc + o];
            wj[k] = wjT[(d + k) * Dc + o];
        }
#pragma unroll
        for (int t = 0; t < TN; ++t) {
            const float4 hv = *reinterpret_cast<const float4*>(&hs[t][d]);
            acci[t] = fmaf(hv.x, wi[0], acci[t]);
            acci[t] = fmaf(hv.y, wi[1], acci[t]);
            acci[t] = fmaf(hv.z, wi[2], acci[t]);
            acci[t] = fmaf(hv.w, wi[3], acci[t]);
            accj[t] = fmaf(hv.x, wj[0], accj[t]);
            accj[t] = fmaf(hv.y, wj[1], accj[t]);
            accj[t] = fmaf(hv.z, wj[2], accj[t]);
            accj[t] = fmaf(hv.w, wj[3], accj[t]);
        }
    }
#pragma unroll
    for (int t = 0; t < TN; ++t) {
        ai[(r0 + t) * Dc + o] = acci[t];
        aj[(r0 + t) * Dc + o] = accj[t];
    }
}

// --- fused msg + lin2 + residual. grid = BN/TI = 256 blocks, 512 threads.
__global__ __launch_bounds__(512) void gnn_msgfull(const float* __restrict__ ai,
                                                   const float* __restrict__ aj,
                                                   const float* __restrict__ adj,
                                                   const float* __restrict__ hin,
                                                   const float* __restrict__ w2T,
                                                   const float* __restrict__ b2,
                                                   float* __restrict__ hout) {
    __shared__ __align__(16) float ajs[CH][Dc];    // 32 KB (reused as red4)
    __shared__ __align__(16) float adjsT[Nc][TI];  // 16 KB
    __shared__ float s_lds[TI][Dc];                // 4 KB
    __shared__ float redw[8][TI];
    __shared__ float arow_l[TI];

    const int tid = threadIdx.x;
    const int dg = tid & 31;   // d-quad: d = dg*4 .. dg*4+3
    const int jg = tid >> 5;   // j-group 0..15
    const int lane = tid & 63;
    const int w = tid >> 6;    // wave 0..7
    const int r0 = blockIdx.x * TI;
    const int b = r0 / Nc;
    const int i0 = r0 - b * Nc;
    const float* __restrict__ ajb = aj + (size_t)b * Nc * Dc;
    const float* __restrict__ adjb = adj + (size_t)b * Nc * Nc;

    float4 tmpA[4], tmpB[4];

#define STAGE_LOAD(T, c)                                                          \
    {                                                                             \
        _Pragma("unroll") for (int q = 0; q < 4; ++q) {                           \
            const int f = tid * 4 + q;                                            \
            T[q] = *reinterpret_cast<const float4*>(                              \
                &ajb[(size_t)((c)*CH + (f >> 5)) * Dc + (f & 31) * 4]);           \
        }                                                                         \
    }
#define STAGE_STORE(T)                                                            \
    {                                                                             \
        _Pragma("unroll") for (int q = 0; q < 4; ++q) {                           \
            const int f = tid * 4 + q;                                            \
            *reinterpret_cast<float4*>(&ajs[f >> 5][(f & 31) * 4]) = T[q];        \
        }                                                                         \
    }

    STAGE_LOAD(tmpA, 0);  // chunk 0 in flight

    // ---- stage adjsT: thread = column j (coalesced reads per row)
    {
        float av[TI];
#pragma unroll
        for (int r = 0; r < TI; ++r) av[r] = adjb[(size_t)(i0 + r) * Nc + tid];
        *reinterpret_cast<float4*>(&adjsT[tid][0]) =
            make_float4(av[0], av[1], av[2], av[3]);
        *reinterpret_cast<float4*>(&adjsT[tid][4]) =
            make_float4(av[4], av[5], av[6], av[7]);
        // arow partials: full-wave shfl reduce per row
#pragma unroll
        for (int r = 0; r < TI; ++r) {
            float p = av[r];
#pragma unroll
            for (int m = 32; m >= 1; m >>= 1) p += __shfl_xor(p, m);
            if (lane == 0) redw[w][r] = p;
        }
    }

    float4 x4[TI], acc4[TI];
#pragma unroll
    for (int r = 0; r < TI; ++r) {
        x4[r] = *reinterpret_cast<const float4*>(&ai[(size_t)(r0 + r) * Dc + dg * 4]);
        acc4[r] = make_float4(0.f, 0.f, 0.f, 0.f);
    }

#define ROWFMA(r, a)                                                   \
    acc4[r].x = fmaf(a, fmaxf(x4[r].x + v4.x, 0.f), acc4[r].x);        \
    acc4[r].y = fmaf(a, fmaxf(x4[r].y + v4.y, 0.f), acc4[r].y);        \
    acc4[r].z = fmaf(a, fmaxf(x4[r].z + v4.z, 0.f), acc4[r].z);        \
    acc4[r].w = fmaf(a, fmaxf(x4[r].w + v4.w, 0.f), acc4[r].w);

#define CONSUME(c)                                                                 \
    {                                                                              \
        _Pragma("unroll") for (int jj = 0; jj < 4; ++jj) {                         \
            const int jl = jg * 4 + jj;                                            \
            const float4 v4 = *reinterpret_cast<const float4*>(&ajs[jl][dg * 4]);  \
            const float4 a0 =                                                      \
                *reinterpret_cast<const float4*>(&adjsT[(c)*CH + jl][0]);          \
            const float4 a1 =                                                      \
                *reinterpret_cast<const float4*>(&adjsT[(c)*CH + jl][4]);          \
            ROWFMA(0, a0.x) ROWFMA(1, a0.y) ROWFMA(2, a0.z) ROWFMA(3, a0.w)        \
            ROWFMA(4, a1.x) ROWFMA(5, a1.y) ROWFMA(6, a1.z) ROWFMA(7, a1.w)        \
        }                                                                          \
    }

    for (int c = 0; c < NCH; c += 2) {
        STAGE_STORE(tmpA);
        STAGE_LOAD(tmpB, c + 1);
        __syncthreads();          // ajs chunk c ready (also fences adjsT first time)
        CONSUME(c);
        __syncthreads();
        STAGE_STORE(tmpB);
        if (c + 2 < NCH) STAGE_LOAD(tmpA, c + 2);
        __syncthreads();          // ajs chunk c+1 ready
        CONSUME(c + 1);
        __syncthreads();
    }

    // ---- reduce over 16 j-groups
#pragma unroll
    for (int r = 0; r < TI; ++r) {  // combine jg pairs within wave
        acc4[r].x += __shfl_xor(acc4[r].x, 32);
        acc4[r].y += __shfl_xor(acc4[r].y, 32);
        acc4[r].z += __shfl_xor(acc4[r].z, 32);
        acc4[r].w += __shfl_xor(acc4[r].w, 32);
    }
    float4* red4 = reinterpret_cast<float4*>(&ajs[0][0]);  // ajs dead; reuse
    if (lane < 32) {
#pragma unroll
        for (int r = 0; r < TI; ++r) red4[w * 256 + r * 32 + dg] = acc4[r];
    }
    __syncthreads();
    if (tid < 256) {
        const int rr = tid >> 5, dq = tid & 31;
        float4 s4 = red4[rr * 32 + dq];
#pragma unroll
        for (int ww = 1; ww < 8; ++ww) {
            const float4 t4 = red4[ww * 256 + rr * 32 + dq];
            s4.x += t4.x; s4.y += t4.y; s4.z += t4.z; s4.w += t4.w;
        }
        *reinterpret_cast<float4*>(&s_lds[rr][dq * 4]) = s4;
    }
    if (tid < TI) {
        float p = 0.f;
#pragma unroll
        for (int ww = 0; ww < 8; ++ww) p += redw[ww][tid];
        arow_l[tid] = p;
    }
    __syncthreads();

    // ---- fused lin2 + residual: thread = (o, row-pair {rq, rq+4})
    {
        const int o = tid & 127;
        const int rq = tid >> 7;  // 0..3
        float accA = 0.f, accB = 0.f;
        for (int dd = 0; dd < Dc; dd += 4) {
            const float w0 = w2T[(size_t)(dd + 0) * Dc + o];
            const float w1 = w2T[(size_t)(dd + 1) * Dc + o];
            const float w2v = w2T[(size_t)(dd + 2) * Dc + o];
            const float w3 = w2T[(size_t)(dd + 3) * Dc + o];
            const float4 sA = *reinterpret_cast<const float4*>(&s_lds[rq][dd]);
            const float4 sB = *reinterpret_cast<const float4*>(&s_lds[rq + 4][dd]);
            accA = fmaf(sA.x, w0, accA); accA = fmaf(sA.y, w1, accA);
            accA = fmaf(sA.z, w2v, accA); accA = fmaf(sA.w, w3, accA);
            accB = fmaf(sB.x, w0, accB); accB = fmaf(sB.y, w1, accB);
            accB = fmaf(sB.z, w2v, accB); accB = fmaf(sB.w, w3, accB);
        }
        const float b2o = b2[o];
        hout[(size_t)(r0 + rq) * Dc + o] =
            hin[(size_t)(r0 + rq) * Dc + o] + accA + arow_l[rq] * b2o;
        hout[(size_t)(r0 + rq + 4) * Dc + o] =
            hin[(size_t)(r0 + rq + 4) * Dc + o] + accB + arow_l[rq + 4] * b2o;
    }
#undef STAGE_LOAD
#undef STAGE_STORE
#undef CONSUME
#undef ROWFMA
}

extern "C" void kernel_launch(void* const* d_in, const int* in_sizes, int n_in,
                              void* d_out, int out_size, void* d_ws, size_t ws_size,
                              hipStream_t stream) {
    const float* node = (const float*)d_in[0];
    const float* adj  = (const float*)d_in[1];
    const float* w1   = (const float*)d_in[2];
    const float* b1   = (const float*)d_in[3];
    const float* w2   = (const float*)d_in[4];
    const float* b2   = (const float*)d_in[5];
    float* out = (float*)d_out;

    float* ws = (float*)d_ws;
    float* wiT = ws; ws += Lc * Dc * Dc;
    float* wjT = ws; ws += Lc * Dc * Dc;
    float* w2T = ws; ws += Lc * Dc * Dc;
    float* ai  = ws; ws += BN * Dc;
    float* aj  = ws; ws += BN * Dc;
    float* h1  = ws; ws += BN * Dc;

    transpose_w_kernel<<<(Lc * Dc * Dc + 255) / 256, 256, 0, stream>>>(w1, w2, wiT,
                                                                       wjT, w2T);
    // layer 0
    gnn_lin1<<<BN / TN, 128, 0, stream>>>(node, wiT, wjT, b1, ai, aj);
    gnn_msgfull<<<BN / TI, 512, 0, stream>>>(ai, aj, adj, node, w2T, b2, h1);
    // layer 1
    gnn_lin1<<<BN / TN, 128, 0, stream>>>(h1, wiT + Dc * Dc, wjT + Dc * Dc, b1 + Dc,
                                          ai, aj);
    gnn_msgfull<<<BN / TI, 512, 0, stream>>>(ai, aj, adj, h1, w2T + Dc * Dc,
                                             b2 + Dc, out);
}

// Round 7
// 74.303 us; speedup vs baseline: 1.2390x; 1.2390x over previous
//
#include <hip/hip_runtime.h>

// SimpleGNN: B=4, N=512, D=128, L=2
// msg[b,i,:] = (sum_j adj[b,i,j]*relu(ai'[b,i,:]+aj[b,j,:])) @ w2^T
//            + (sum_j adj[b,i,j]) * b2 ;  ai' = h@wi^T + b1, aj = h@wj^T
// msg v5: barrier-free streaming waves + TLP. Block = 2 rows, 4 waves; each
// wave owns a 128-j slice and streams aj straight from L2 (coalesced float2,
// 8 loads in flight). adj for the 2 rows sits in LDS as [j][r] so ONE
// broadcast ds_read_b64 feeds both rows. 2 barriers per block total.
// 1024 blocks = 4 blocks/CU = 16 waves/CU -> latency hidden by TLP, not
// by intra-block pipelining (which hipcc defeats via vmcnt(0)-before-barrier).

constexpr int Bc = 4, Nc = 512, Dc = 128, Lc = 2;
constexpr int BN = Bc * Nc;  // 2048
constexpr int TIB = 2;       // rows per msg block
constexpr int TN = 4;        // rows per lin block

__global__ void transpose_w_kernel(const float* __restrict__ w1,
                                   const float* __restrict__ w2,
                                   float* __restrict__ wiT,
                                   float* __restrict__ wjT,
                                   float* __restrict__ w2T) {
    int idx = blockIdx.x * blockDim.x + threadIdx.x;
    if (idx >= Lc * Dc * Dc) return;
    int l = idx / (Dc * Dc);
    int rem = idx - l * Dc * Dc;
    int d = rem / Dc;
    int o = rem - d * Dc;
    wiT[idx] = w1[(l * Dc + o) * (2 * Dc) + d];
    wjT[idx] = w1[(l * Dc + o) * (2 * Dc) + Dc + d];
    w2T[idx] = w2[(l * Dc + o) * Dc + d];
}

// --- first linear (round-3 winner, verbatim)
__global__ __launch_bounds__(128) void gnn_lin1(const float* __restrict__ h,
                                                const float* __restrict__ wiT,
                                                const float* __restrict__ wjT,
                                                const float* __restrict__ b1,
                                                float* __restrict__ ai,
                                                float* __restrict__ aj) {
    __shared__ float hs[TN][Dc];
    const int o = threadIdx.x;
    const int r0 = blockIdx.x * TN;
#pragma unroll
    for (int t = 0; t < TN; ++t) hs[t][o] = h[(r0 + t) * Dc + o];
    __syncthreads();
    float acci[TN], accj[TN];
    const float bo = b1[o];
#pragma unroll
    for (int t = 0; t < TN; ++t) { acci[t] = bo; accj[t] = 0.f; }
    for (int d = 0; d < Dc; d += 4) {
        float wi[4], wj[4];
#pragma unroll
        for (int k = 0; k < 4; ++k) {
            wi[k] = wiT[(d + k) * Dc + o];
            wj[k] = wjT[(d + k) * Dc + o];
        }
#pragma unroll
        for (int t = 0; t < TN; ++t) {
            const float4 hv = *reinterpret_cast<const float4*>(&hs[t][d]);
            acci[t] = fmaf(hv.x, wi[0], acci[t]);
            acci[t] = fmaf(hv.y, wi[1], acci[t]);
            acci[t] = fmaf(hv.z, wi[2], acci[t]);
            acci[t] = fmaf(hv.w, wi[3], acci[t]);
            accj[t] = fmaf(hv.x, wj[0], accj[t]);
            accj[t] = fmaf(hv.y, wj[1], accj[t]);
            accj[t] = fmaf(hv.z, wj[2], accj[t]);
            accj[t] = fmaf(hv.w, wj[3], accj[t]);
        }
    }
#pragma unroll
    for (int t = 0; t < TN; ++t) {
        ai[(r0 + t) * Dc + o] = acci[t];
        aj[(r0 + t) * Dc + o] = accj[t];
    }
}

// --- msg v5: s[r][d] = sum_j adj[b,i,j]*relu(ai[r][d]+aj[b,j,d]);
//             arow[r] = sum_j adj[b,i,j]
// grid = BN/TIB = 1024 blocks, 256 threads (4 waves, each owns 128 j's).
__global__ __launch_bounds__(256) void gnn_msg(const float* __restrict__ ai,
                                               const float* __restrict__ aj,
                                               const float* __restrict__ adj,
                                               float* __restrict__ s,
                                               float* __restrict__ arow) {
    __shared__ float adjs[Nc][TIB];       // [j][r], 4 KB
    __shared__ float red[4][TIB][Dc];     // wave partials, 4 KB
    __shared__ float redw[4];             // arow wave partials

    const int tid = threadIdx.x;
    const int w = tid >> 6;    // wave 0..3
    const int lane = tid & 63;
    const int r0 = blockIdx.x * TIB;
    const int b = r0 / Nc;
    const int i0 = r0 - b * Nc;
    const float* __restrict__ ajb = aj + (size_t)b * Nc * Dc;
    const float* __restrict__ adjb = adj + (size_t)b * Nc * Nc;

    // ---- stage adj rows (interleaved [j][r]) + arow wave partials.
    // waves 0,1 cover row 0; waves 2,3 cover row 1 (tid>>7).
    {
        const int sr = tid >> 7;
        const int sc4 = (tid & 127) * 4;
        const float4 av =
            *reinterpret_cast<const float4*>(&adjb[(size_t)(i0 + sr) * Nc + sc4]);
        adjs[sc4 + 0][sr] = av.x;
        adjs[sc4 + 1][sr] = av.y;
        adjs[sc4 + 2][sr] = av.z;
        adjs[sc4 + 3][sr] = av.w;
        float p = av.x + av.y + av.z + av.w;
#pragma unroll
        for (int m = 32; m >= 1; m >>= 1) p += __shfl_xor(p, m);
        if (lane == 0) redw[w] = p;
    }

    // ---- per-lane state: d-pair (2*lane, 2*lane+1)
    const int d0 = lane * 2;
    float2 x[TIB], acc[TIB];
#pragma unroll
    for (int r = 0; r < TIB; ++r) {
        x[r] = *reinterpret_cast<const float2*>(&ai[(size_t)(r0 + r) * Dc + d0]);
        acc[r] = make_float2(0.f, 0.f);
    }
    __syncthreads();

    // ---- barrier-free stream over this wave's 128 j's
    const float* __restrict__ ajw = ajb + (size_t)(w * 128) * Dc + d0;
#pragma unroll 8
    for (int jj = 0; jj < 128; ++jj) {
        const float2 v = *reinterpret_cast<const float2*>(&ajw[(size_t)jj * Dc]);
        const float2 a = *reinterpret_cast<const float2*>(&adjs[w * 128 + jj][0]);
        acc[0].x = fmaf(a.x, fmaxf(x[0].x + v.x, 0.f), acc[0].x);
        acc[0].y = fmaf(a.x, fmaxf(x[0].y + v.y, 0.f), acc[0].y);
        acc[1].x = fmaf(a.y, fmaxf(x[1].x + v.x, 0.f), acc[1].x);
        acc[1].y = fmaf(a.y, fmaxf(x[1].y + v.y, 0.f), acc[1].y);
    }

    // ---- cross-wave reduce
#pragma unroll
    for (int r = 0; r < TIB; ++r)
        *reinterpret_cast<float2*>(&red[w][r][d0]) = acc[r];
    __syncthreads();
    {
        const int rr = tid >> 7;
        const int dd = tid & 127;
        const float sv = red[0][rr][dd] + red[1][rr][dd] + red[2][rr][dd] +
                         red[3][rr][dd];
        s[(size_t)(r0 + rr) * Dc + dd] = sv;
    }
    if (tid < TIB) arow[r0 + tid] = redw[2 * tid] + redw[2 * tid + 1];
}

// --- final second linear + residual
__global__ __launch_bounds__(128) void gnn_lin2(const float* __restrict__ hin,
                                                const float* __restrict__ s,
                                                const float* __restrict__ arow,
                                                const float* __restrict__ w2T,
                                                const float* __restrict__ b2,
                                                float* __restrict__ hout) {
    __shared__ float ss[TN][Dc];
    const int o = threadIdx.x;
    const int r0 = blockIdx.x * TN;
#pragma unroll
    for (int t = 0; t < TN; ++t) ss[t][o] = s[(size_t)(r0 + t) * Dc + o];
    __syncthreads();
    float acc[TN];
#pragma unroll
    for (int t = 0; t < TN; ++t) acc[t] = 0.f;
    for (int d = 0; d < Dc; d += 4) {
        float w[4];
#pragma unroll
        for (int k = 0; k < 4; ++k) w[k] = w2T[(d + k) * Dc + o];
#pragma unroll
        for (int t = 0; t < TN; ++t) {
            const float4 sv = *reinterpret_cast<const float4*>(&ss[t][d]);
            acc[t] = fmaf(sv.x, w[0], acc[t]);
            acc[t] = fmaf(sv.y, w[1], acc[t]);
            acc[t] = fmaf(sv.z, w[2], acc[t]);
            acc[t] = fmaf(sv.w, w[3], acc[t]);
        }
    }
    const float b2o = b2[o];
#pragma unroll
    for (int t = 0; t < TN; ++t)
        hout[(r0 + t) * Dc + o] =
            hin[(r0 + t) * Dc + o] + acc[t] + arow[r0 + t] * b2o;
}

// --- fused: lin2 of layer l + residual, then lin1 of layer l+1.
__global__ __launch_bounds__(128) void gnn_lin2lin1(const float* __restrict__ hin,
                                                    const float* __restrict__ s,
                                                    const float* __restrict__ arow,
                                                    const float* __restrict__ w2T,
                                                    const float* __restrict__ b2,
                                                    const float* __restrict__ wiT,
                                                    const float* __restrict__ wjT,
                                                    const float* __restrict__ b1,
                                                    float* __restrict__ hout,
                                                    float* __restrict__ ai,
                                                    float* __restrict__ aj) {
    __shared__ float ss[TN][Dc];
    const int o = threadIdx.x;
    const int r0 = blockIdx.x * TN;
#pragma unroll
    for (int t = 0; t < TN; ++t) ss[t][o] = s[(size_t)(r0 + t) * Dc + o];
    __syncthreads();
    float acc[TN];
#pragma unroll
    for (int t = 0; t < TN; ++t) acc[t] = 0.f;
    for (int d = 0; d < Dc; d += 4) {
        float w[4];
#pragma unroll
        for (int k = 0; k < 4; ++k) w[k] = w2T[(d + k) * Dc + o];
#pragma unroll
        for (int t = 0; t < TN; ++t) {
            const float4 sv = *reinterpret_cast<const float4*>(&ss[t][d]);
            acc[t] = fmaf(sv.x, w[0], acc[t]);
            acc[t] = fmaf(sv.y, w[1], acc[t]);
            acc[t] = fmaf(sv.z, w[2], acc[t]);
            acc[t] = fmaf(sv.w, w[3], acc[t]);
        }
    }
    const float b2o = b2[o];
    float hnew[TN];
#pragma unroll
    for (int t = 0; t < TN; ++t) {
        hnew[t] = hin[(r0 + t) * Dc + o] + acc[t] + arow[r0 + t] * b2o;
        hout[(r0 + t) * Dc + o] = hnew[t];
    }
    __syncthreads();
#pragma unroll
    for (int t = 0; t < TN; ++t) ss[t][o] = hnew[t];
    __syncthreads();
    float acci[TN], accj[TN];
    const float bo = b1[o];
#pragma unroll
    for (int t = 0; t < TN; ++t) { acci[t] = bo; accj[t] = 0.f; }
    for (int d = 0; d < Dc; d += 4) {
        float wi[4], wj[4];
#pragma unroll
        for (int k = 0; k < 4; ++k) {
            wi[k] = wiT[(d + k) * Dc + o];
            wj[k] = wjT[(d + k) * Dc + o];
        }
#pragma unroll
        for (int t = 0; t < TN; ++t) {
            const float4 hv = *reinterpret_cast<const float4*>(&ss[t][d]);
            acci[t] = fmaf(hv.x, wi[0], acci[t]);
            acci[t] = fmaf(hv.y, wi[1], acci[t]);
            acci[t] = fmaf(hv.z, wi[2], acci[t]);
            acci[t] = fmaf(hv.w, wi[3], acci[t]);
            accj[t] = fmaf(hv.x, wj[0], accj[t]);
            accj[t] = fmaf(hv.y, wj[1], accj[t]);
            accj[t] = fmaf(hv.z, wj[2], accj[t]);
            accj[t] = fmaf(hv.w, wj[3], accj[t]);
        }
    }
#pragma unroll
    for (int t = 0; t < TN; ++t) {
        ai[(r0 + t) * Dc + o] = acci[t];
        aj[(r0 + t) * Dc + o] = accj[t];
    }
}

extern "C" void kernel_launch(void* const* d_in, const int* in_sizes, int n_in,
                              void* d_out, int out_size, void* d_ws, size_t ws_size,
                              hipStream_t stream) {
    const float* node = (const float*)d_in[0];
    const float* adj  = (const float*)d_in[1];
    const float* w1   = (const float*)d_in[2];
    const float* b1   = (const float*)d_in[3];
    const float* w2   = (const float*)d_in[4];
    const float* b2   = (const float*)d_in[5];
    float* out = (float*)d_out;

    float* ws = (float*)d_ws;
    float* wiT = ws; ws += Lc * Dc * Dc;
    float* wjT = ws; ws += Lc * Dc * Dc;
    float* w2T = ws; ws += Lc * Dc * Dc;
    float* ai  = ws; ws += BN * Dc;
    float* aj  = ws; ws += BN * Dc;
    float* sb  = ws; ws += BN * Dc;
    float* arow= ws; ws += BN;
    float* h1  = ws; ws += BN * Dc;

    transpose_w_kernel<<<(Lc * Dc * Dc + 255) / 256, 256, 0, stream>>>(w1, w2, wiT,
                                                                       wjT, w2T);
    // layer 0
    gnn_lin1<<<BN / TN, 128, 0, stream>>>(node, wiT, wjT, b1, ai, aj);
    gnn_msg<<<BN / TIB, 256, 0, stream>>>(ai, aj, adj, sb, arow);
    gnn_lin2lin1<<<BN / TN, 128, 0, stream>>>(node, sb, arow, w2T, b2,
                                              wiT + Dc * Dc, wjT + Dc * Dc, b1 + Dc,
                                              h1, ai, aj);
    // layer 1
    gnn_msg<<<BN / TIB, 256, 0, stream>>>(ai, aj, adj, sb, arow);
    gnn_lin2<<<BN / TN, 128, 0, stream>>>(h1, sb, arow, w2T + Dc * Dc, b2 + Dc, out);
}